// Round 5
// baseline (224.659 us; speedup 1.0000x reference)
//
#include <hip/hip_runtime.h>

typedef __bf16 bf16_t;
typedef __bf16 bf16x8 __attribute__((ext_vector_type(8)));
typedef __bf16 bf16x4 __attribute__((ext_vector_type(4)));
typedef float f32x4 __attribute__((ext_vector_type(4)));

static __device__ __forceinline__ f32x4 mfma16(bf16x8 a, bf16x8 b, f32x4 c) {
    return __builtin_amdgcn_mfma_f32_16x16x32_bf16(a, b, c, 0, 0, 0);
}

#define AS1 __attribute__((address_space(1)))
#define AS3 __attribute__((address_space(3)))
static __device__ __forceinline__ void gload16(const void* g, void* l) {
    __builtin_amdgcn_global_load_lds((AS1 const void*)g, (AS3 void*)l, 16, 0, 0);
}

constexpr int B_ = 2, S_ = 2048, H_ = 16, DH = 128, AF = 2048;
constexpr int M_ = B_ * S_;  // 4096

// ---------------- f32 -> bf16 convert (query) ----------------
__global__ void cvt_f32_to_bf16(const float* __restrict__ in, bf16_t* __restrict__ out) {
    int i = (blockIdx.x * 256 + threadIdx.x) * 4;
    const float4 v = *reinterpret_cast<const float4*>(in + i);
    bf16x4 o = { (bf16_t)v.x, (bf16_t)v.y, (bf16_t)v.z, (bf16_t)v.w };
    *reinterpret_cast<bf16x4*>(out + i) = o;
}

// ---------------- f32 [R][C] -> bf16 [C][R] transpose ----------------
__global__ void transpose_to_bf16(const float* __restrict__ in, bf16_t* __restrict__ out,
                                  int R, int C) {
    __shared__ float t[32][33];
    int c0 = blockIdx.x * 32, r0 = blockIdx.y * 32;
    int tx = threadIdx.x & 31, ty = threadIdx.x >> 5;  // 32 x 8
#pragma unroll
    for (int i = 0; i < 4; i++) t[ty + i * 8][tx] = in[(size_t)(r0 + ty + i * 8) * C + c0 + tx];
    __syncthreads();
#pragma unroll
    for (int i = 0; i < 4; i++)
        out[(size_t)(c0 + ty + i * 8) * R + r0 + tx] = (bf16_t)t[tx][ty + i * 8];
}

// ---------------- 128x128-tile bf16 GEMM: C = A[M][K] * Bt[N][K]^T + bias ----------------
// v5: staging via global_load_lds width=16 (linear LDS dest, pre-swizzled source col).
template <int K, int N, bool OUTBF16, bool QKV>
__global__ __launch_bounds__(256) void gemm128(
    const bf16_t* __restrict__ A, const bf16_t* __restrict__ Bt,
    const float* __restrict__ b0, const float* __restrict__ b1, const float* __restrict__ b2,
    bf16_t* __restrict__ Cqk, bf16_t* __restrict__ Vt, float* __restrict__ Cf) {
    __shared__ bf16_t As[128 * 64];
    __shared__ bf16_t Bs[128 * 64];
    const int z = blockIdx.z;
    const bf16_t* Bz = Bt + (size_t)z * N * K;
    const float* bias = (z == 0) ? b0 : (z == 1 ? b1 : b2);
    const int m0 = blockIdx.y * 128, n0 = blockIdx.x * 128;
    const int tid = threadIdx.x, lane = tid & 63, wave = tid >> 6;
    const int wm = (wave >> 1) * 64, wn = (wave & 1) * 64;
    const int fr = lane & 15, fq = lane >> 4;

    f32x4 acc[4][4];
    const f32x4 fz = {0.f, 0.f, 0.f, 0.f};
#pragma unroll
    for (int i = 0; i < 4; i++)
#pragma unroll
        for (int j = 0; j < 4; j++) acc[i][j] = fz;

    for (int kt = 0; kt < K / 64; ++kt) {
        const int k0 = kt * 64;
#pragma unroll
        for (int j = 0; j < 4; j++) {
            int cid = tid + 256 * j;              // 16B chunk id, 0..1023
            int r = cid >> 3;                     // tile row 0..127
            int sc = ((cid & 7) ^ (r & 7)) << 3;  // pre-swizzled source col (elements)
            gload16(A + (size_t)(m0 + r) * K + k0 + sc, (char*)As + cid * 16);
            gload16(Bz + (size_t)(n0 + r) * K + k0 + sc, (char*)Bs + cid * 16);
        }
        __syncthreads();  // drains vmcnt -> tile staged
#pragma unroll
        for (int ks = 0; ks < 2; ++ks) {
            bf16x8 af[4], bfv[4];
#pragma unroll
            for (int mi = 0; mi < 4; mi++) {
                int r = wm + mi * 16 + fr;
                int cb = (ks * 64 + fq * 16) ^ ((r & 7) << 4);
                af[mi] = *reinterpret_cast<const bf16x8*>(reinterpret_cast<const char*>(As) + r * 128 + cb);
            }
#pragma unroll
            for (int ni = 0; ni < 4; ni++) {
                int r = wn + ni * 16 + fr;
                int cb = (ks * 64 + fq * 16) ^ ((r & 7) << 4);
                bfv[ni] = *reinterpret_cast<const bf16x8*>(reinterpret_cast<const char*>(Bs) + r * 128 + cb);
            }
            __builtin_amdgcn_s_setprio(1);
#pragma unroll
            for (int mi = 0; mi < 4; mi++)
#pragma unroll
                for (int ni = 0; ni < 4; ni++) acc[mi][ni] = mfma16(af[mi], bfv[ni], acc[mi][ni]);
            __builtin_amdgcn_s_setprio(0);
        }
        __syncthreads();  // reads done before next tile's gload_lds overwrites
    }

#pragma unroll
    for (int ni = 0; ni < 4; ni++) {
        const int col = n0 + wn + ni * 16 + fr;
        const float bb = bias[col];
#pragma unroll
        for (int mi = 0; mi < 4; mi++) {
            const int mrow = m0 + wm + mi * 16 + fq * 4;
            f32x4 v = acc[mi][ni];
            if (OUTBF16) {
                if (QKV && z == 2) {
                    const int b = mrow >> 11, s = mrow & (S_ - 1);
                    const int h = col >> 7, d = col & (DH - 1);
                    bf16x4 w = { (bf16_t)(v[0] + bb), (bf16_t)(v[1] + bb),
                                 (bf16_t)(v[2] + bb), (bf16_t)(v[3] + bb) };
                    *reinterpret_cast<bf16x4*>(Vt + ((size_t)((b * H_ + h) * DH + d)) * S_ + s) = w;
                } else {
                    bf16_t* Cz = Cqk + (size_t)z * M_ * N;
#pragma unroll
                    for (int j = 0; j < 4; j++)
                        Cz[(size_t)(mrow + j) * N + col] = (bf16_t)(v[j] + bb);
                }
            } else {
#pragma unroll
                for (int j = 0; j < 4; j++) Cf[(size_t)(mrow + j) * N + col] = v[j] + bb;
            }
        }
    }
}

// ---------------- causal flash attention, v4 ----------------
// v4: KVBLK=32 -> LDS 40960 B (Ks 2x8K, Vs 2x8K, Pl 8K) so 2+ blocks/CU actually fit
// (R4's 81920 x2 == exactly 160 KiB and the HW refused to co-schedule).
// 512 blocks: id -> bh = id&31, qt = (j<8 ? j : 23-j); NT = 4qt+4 tiles of 32 kv.
// Swapped QK^T (lane owns one q-row), defer-max (T13), setprio (T5), gload_lds staging
// with both-sides XOR swizzle: K rows 256B ^(r&7), V rows 64B ^(rv&3), Pl rows 64B ^(q&3).
constexpr int KBUF = 32 * 128 * (int)sizeof(bf16_t);  // 8192 B per K buffer (== V buffer)

__global__ __launch_bounds__(256, 2) void attn(
    const bf16_t* __restrict__ Q, const bf16_t* __restrict__ Kc,
    const bf16_t* __restrict__ Vt, bf16_t* __restrict__ Ctx) {
    const int id = blockIdx.x;
    const int bh = id & 31, b = bh >> 4, h = bh & 15;
    const int j = id >> 5;
    const int qt = (j < 8) ? j : 23 - j;
    const int q0 = qt * 128;
    const int NT = 4 * qt + 4;
    const int lane = threadIdx.x & 63, wave = threadIdx.x >> 6;
    const int fr = lane & 15, fq = lane >> 4;

    __shared__ bf16_t Ks[2][32 * 128];   // 16 KB
    __shared__ bf16_t Vs[2][128 * 32];   // 16 KB
    __shared__ bf16_t Pl[4][32][32];     //  8 KB, XOR-swizzled

    const bf16_t* Kbase = Kc + (size_t)b * S_ * AF + h * DH;
    const bf16_t* Vbase = Vt + (size_t)bh * DH * S_;
    const float scale = 0.022097086912079608f;  // 1/sqrt(2048)
    const f32x4 fz = {0.f, 0.f, 0.f, 0.f};

    auto stage = [&](int buf, int kv0) {
#pragma unroll
        for (int i = 0; i < 2; ++i) {   // K tile [32 kv][128 dh], rows 256 B = 16 chunks
            const int c = wave * 128 + i * 64 + lane;
            const int r = c >> 4;
            const bf16_t* src = Kbase + (size_t)(kv0 + r) * AF + (((lane & 15) ^ (r & 7)) << 3);
            gload16(src, (char*)Ks + buf * KBUF + c * 16);
        }
#pragma unroll
        for (int i = 0; i < 2; ++i) {   // V tile [128 d][32 kv], rows 64 B = 4 chunks
            const int c = wave * 128 + i * 64 + lane;
            const int rv = c >> 2;
            const bf16_t* src = Vbase + (size_t)rv * S_ + kv0 + (((lane & 3) ^ (rv & 3)) << 3);
            gload16(src, (char*)Vs + buf * KBUF + c * 16);
        }
    };

    // Q fragments: wave rows q0 + wave*32 + qg*16 + fr
    bf16x8 qf[2][4];
#pragma unroll
    for (int qg = 0; qg < 2; ++qg) {
        const bf16_t* qp = Q + (size_t)(b * S_ + q0 + wave * 32 + qg * 16 + fr) * AF + h * DH + fq * 8;
#pragma unroll
        for (int ds = 0; ds < 4; ++ds) qf[qg][ds] = *reinterpret_cast<const bf16x8*>(qp + ds * 32);
    }
    float m_[2] = {-3.0e38f, -3.0e38f}, l_[2] = {0.f, 0.f};
    f32x4 o[2][8];
#pragma unroll
    for (int qg = 0; qg < 2; ++qg)
#pragma unroll
        for (int d = 0; d < 8; ++d) o[qg][d] = fz;

    stage(0, 0);
    __syncthreads();  // tile 0 ready

    char* PlB = reinterpret_cast<char*>(Pl) + wave * 2048;

    for (int t = 0; t < NT; ++t) {
        const int cur = t & 1;
        if (t + 1 < NT) stage(cur ^ 1, (t + 1) * 32);
        const int kv0 = t * 32;
        const char* kb = (const char*)Ks + cur * KBUF;
        const char* vb = (const char*)Vs + cur * KBUF;

        // ---- QK^T (swapped): sv[qg][kvf][r] = S[kv=kvf*16+fq*4+r][q=fr] ----
        f32x4 sv[2][2];
        __builtin_amdgcn_s_setprio(1);
#pragma unroll
        for (int kvf = 0; kvf < 2; ++kvf) {
            bf16x8 kf[4];
#pragma unroll
            for (int ds = 0; ds < 4; ++ds) {
                const int r = kvf * 16 + fr;
                kf[ds] = *reinterpret_cast<const bf16x8*>(kb + r * 256 + ((ds * 64 + fq * 16) ^ ((r & 7) << 4)));
            }
            sv[0][kvf] = fz; sv[1][kvf] = fz;
#pragma unroll
            for (int ds = 0; ds < 4; ++ds) {
                sv[0][kvf] = mfma16(kf[ds], qf[0][ds], sv[0][kvf]);
                sv[1][kvf] = mfma16(kf[ds], qf[1][ds], sv[1][kvf]);
            }
        }
        __builtin_amdgcn_s_setprio(0);
        const bool diag = (t >= 4 * qt);

        // ---- softmax (lane owns 8 scores of q-row q0+wave*32+qg*16+fr) ----
#pragma unroll
        for (int qg = 0; qg < 2; ++qg) {
            const int q_abs = q0 + wave * 32 + qg * 16 + fr;
            float x[8], mx = -3.0e38f;
#pragma unroll
            for (int kvf = 0; kvf < 2; ++kvf)
#pragma unroll
                for (int r = 0; r < 4; ++r) {
                    float tv = sv[qg][kvf][r] * scale;
                    if (diag && (kv0 + kvf * 16 + fq * 4 + r > q_abs)) tv = -3.0e38f;
                    x[kvf * 4 + r] = tv;
                    mx = fmaxf(mx, tv);
                }
            mx = fmaxf(mx, __shfl_xor(mx, 16, 64));
            mx = fmaxf(mx, __shfl_xor(mx, 32, 64));
            float mnew = m_[qg];
            if (!__all(mx <= m_[qg] + 8.f)) {   // defer-max (T13)
                mnew = fmaxf(m_[qg], mx);
                const float corr = __expf(m_[qg] - mnew);
                l_[qg] *= corr;
                float cr[4];
#pragma unroll
                for (int r = 0; r < 4; ++r) cr[r] = __shfl(corr, fq * 4 + r, 64);
#pragma unroll
                for (int d = 0; d < 8; ++d)
#pragma unroll
                    for (int r = 0; r < 4; ++r) o[qg][d][r] *= cr[r];
                m_[qg] = mnew;
            }
            float rs = 0.f;
#pragma unroll
            for (int jj = 0; jj < 8; ++jj) { x[jj] = __expf(x[jj] - mnew); rs += x[jj]; }
            rs += __shfl_xor(rs, 16, 64);
            rs += __shfl_xor(rs, 32, 64);
            l_[qg] += rs;
            // P -> LDS (row q = qg*16+fr, 64-B rows, swizzle ^((q&3)<<4))
#pragma unroll
            for (int kvf = 0; kvf < 2; ++kvf) {
                bf16x4 pw = { (bf16_t)x[kvf * 4 + 0], (bf16_t)x[kvf * 4 + 1],
                              (bf16_t)x[kvf * 4 + 2], (bf16_t)x[kvf * 4 + 3] };
                *reinterpret_cast<bf16x4*>(
                    PlB + (qg * 16 + fr) * 64 + ((kvf * 32 + fq * 8) ^ ((fr & 3) << 4))) = pw;
            }
        }

        // ---- PV: A = P (rows q, 32 kv), B = Vt (rows d, 32 kv) ----
        bf16x8 pa[2];
#pragma unroll
        for (int qg = 0; qg < 2; ++qg)
            pa[qg] = *reinterpret_cast<const bf16x8*>(
                PlB + (qg * 16 + fr) * 64 + ((fq * 16) ^ ((fr & 3) << 4)));
        __builtin_amdgcn_s_setprio(1);
#pragma unroll
        for (int d = 0; d < 8; ++d) {
            const int rv = d * 16 + fr;
            const bf16x8 vf = *reinterpret_cast<const bf16x8*>(
                vb + rv * 64 + ((fq * 16) ^ ((rv & 3) << 4)));
            o[0][d] = mfma16(pa[0], vf, o[0][d]);
            o[1][d] = mfma16(pa[1], vf, o[1][d]);
        }
        __builtin_amdgcn_s_setprio(0);
        __syncthreads();  // next tile staged & current reads done
    }

    // ---- epilogue ----
#pragma unroll
    for (int qg = 0; qg < 2; ++qg) {
        float li[4];
#pragma unroll
        for (int r = 0; r < 4; ++r) li[r] = 1.0f / __shfl(l_[qg], fq * 4 + r, 64);
#pragma unroll
        for (int d = 0; d < 8; ++d)
#pragma unroll
            for (int r = 0; r < 4; ++r) {
                const size_t row = (size_t)(b * S_ + q0 + wave * 32 + qg * 16 + fq * 4 + r);
                Ctx[row * AF + h * DH + d * 16 + fr] = (bf16_t)(o[qg][d][r] * li[r]);
            }
    }
}

extern "C" void kernel_launch(void* const* d_in, const int* in_sizes, int n_in,
                              void* d_out, int out_size, void* d_ws, size_t ws_size,
                              hipStream_t stream) {
    const float* query = (const float*)d_in[0];
    const float* Wq = (const float*)d_in[1];
    const float* bq = (const float*)d_in[2];
    const float* Wk = (const float*)d_in[3];
    const float* bk = (const float*)d_in[4];
    const float* Wv = (const float*)d_in[5];
    const float* bv = (const float*)d_in[6];
    const float* Wo = (const float*)d_in[7];
    const float* bo = (const float*)d_in[8];
    float* out = (float*)d_out;
    char* ws = (char*)d_ws;

    bf16_t* xbf  = (bf16_t*)(ws + 0);
    bf16_t* wtq  = (bf16_t*)(ws + 8388608);
    bf16_t* wto  = (bf16_t*)(ws + 20971520);
    bf16_t* qws  = (bf16_t*)(ws + 25165824);
    bf16_t* vtws = (bf16_t*)(ws + 58720256);
    bf16_t* ctx  = (bf16_t*)(ws + 0);

    cvt_f32_to_bf16<<<4096, 256, 0, stream>>>(query, xbf);
    transpose_to_bf16<<<dim3(64, 32), 256, 0, stream>>>(Wq, wtq, 1024, 2048);
    transpose_to_bf16<<<dim3(64, 32), 256, 0, stream>>>(Wk, wtq + 2097152, 1024, 2048);
    transpose_to_bf16<<<dim3(64, 32), 256, 0, stream>>>(Wv, wtq + 2 * 2097152, 1024, 2048);
    transpose_to_bf16<<<dim3(32, 64), 256, 0, stream>>>(Wo, wto, 2048, 1024);

    gemm128<1024, 2048, true, true><<<dim3(16, 32, 3), 256, 0, stream>>>(
        xbf, wtq, bq, bk, bv, qws, vtws, nullptr);

    attn<<<512, 256, 0, stream>>>(qws, qws + (size_t)4096 * 2048, vtws, ctx);

    gemm128<2048, 1024, false, false><<<dim3(8, 32, 1), 256, 0, stream>>>(
        ctx, wto, bo, bo, bo, nullptr, nullptr, out);
}

// Round 6
// 188.712 us; speedup vs baseline: 1.1905x; 1.1905x over previous
//
#include <hip/hip_runtime.h>

typedef __bf16 bf16_t;
typedef __bf16 bf16x8 __attribute__((ext_vector_type(8)));
typedef __bf16 bf16x4 __attribute__((ext_vector_type(4)));
typedef float f32x4 __attribute__((ext_vector_type(4)));

static __device__ __forceinline__ f32x4 mfma16(bf16x8 a, bf16x8 b, f32x4 c) {
    return __builtin_amdgcn_mfma_f32_16x16x32_bf16(a, b, c, 0, 0, 0);
}

#define AS1 __attribute__((address_space(1)))
#define AS3 __attribute__((address_space(3)))
static __device__ __forceinline__ void gload16(const void* g, void* l) {
    __builtin_amdgcn_global_load_lds((AS1 const void*)g, (AS3 void*)l, 16, 0, 0);
}

constexpr int B_ = 2, S_ = 2048, H_ = 16, DH = 128, AF = 2048;
constexpr int M_ = B_ * S_;  // 4096

// ---------------- f32 -> bf16 convert (query) ----------------
__global__ void cvt_f32_to_bf16(const float* __restrict__ in, bf16_t* __restrict__ out) {
    int i = (blockIdx.x * 256 + threadIdx.x) * 4;
    const float4 v = *reinterpret_cast<const float4*>(in + i);
    bf16x4 o = { (bf16_t)v.x, (bf16_t)v.y, (bf16_t)v.z, (bf16_t)v.w };
    *reinterpret_cast<bf16x4*>(out + i) = o;
}

// ---------------- f32 [R][C] -> bf16 [C][R] transpose ----------------
__global__ void transpose_to_bf16(const float* __restrict__ in, bf16_t* __restrict__ out,
                                  int R, int C) {
    __shared__ float t[32][33];
    int c0 = blockIdx.x * 32, r0 = blockIdx.y * 32;
    int tx = threadIdx.x & 31, ty = threadIdx.x >> 5;  // 32 x 8
#pragma unroll
    for (int i = 0; i < 4; i++) t[ty + i * 8][tx] = in[(size_t)(r0 + ty + i * 8) * C + c0 + tx];
    __syncthreads();
#pragma unroll
    for (int i = 0; i < 4; i++)
        out[(size_t)(c0 + ty + i * 8) * R + r0 + tx] = (bf16_t)t[tx][ty + i * 8];
}

// ---------------- 128x128-tile bf16 GEMM: C = A[M][K] * Bt[N][K]^T + bias ----------------
// staging via global_load_lds width=16 (linear LDS dest, pre-swizzled source col).
template <int K, int N, bool OUTBF16, bool QKV>
__global__ __launch_bounds__(256) void gemm128(
    const bf16_t* __restrict__ A, const bf16_t* __restrict__ Bt,
    const float* __restrict__ b0, const float* __restrict__ b1, const float* __restrict__ b2,
    bf16_t* __restrict__ Cqk, bf16_t* __restrict__ Vt, float* __restrict__ Cf) {
    __shared__ bf16_t As[128 * 64];
    __shared__ bf16_t Bs[128 * 64];
    const int z = blockIdx.z;
    const bf16_t* Bz = Bt + (size_t)z * N * K;
    const float* bias = (z == 0) ? b0 : (z == 1 ? b1 : b2);
    const int m0 = blockIdx.y * 128, n0 = blockIdx.x * 128;
    const int tid = threadIdx.x, lane = tid & 63, wave = tid >> 6;
    const int wm = (wave >> 1) * 64, wn = (wave & 1) * 64;
    const int fr = lane & 15, fq = lane >> 4;

    f32x4 acc[4][4];
    const f32x4 fz = {0.f, 0.f, 0.f, 0.f};
#pragma unroll
    for (int i = 0; i < 4; i++)
#pragma unroll
        for (int j = 0; j < 4; j++) acc[i][j] = fz;

    for (int kt = 0; kt < K / 64; ++kt) {
        const int k0 = kt * 64;
#pragma unroll
        for (int j = 0; j < 4; j++) {
            int cid = tid + 256 * j;              // 16B chunk id, 0..1023
            int r = cid >> 3;                     // tile row 0..127
            int sc = ((cid & 7) ^ (r & 7)) << 3;  // pre-swizzled source col (elements)
            gload16(A + (size_t)(m0 + r) * K + k0 + sc, (char*)As + cid * 16);
            gload16(Bz + (size_t)(n0 + r) * K + k0 + sc, (char*)Bs + cid * 16);
        }
        __syncthreads();  // drains vmcnt -> tile staged
#pragma unroll
        for (int ks = 0; ks < 2; ++ks) {
            bf16x8 af[4], bfv[4];
#pragma unroll
            for (int mi = 0; mi < 4; mi++) {
                int r = wm + mi * 16 + fr;
                int cb = (ks * 64 + fq * 16) ^ ((r & 7) << 4);
                af[mi] = *reinterpret_cast<const bf16x8*>(reinterpret_cast<const char*>(As) + r * 128 + cb);
            }
#pragma unroll
            for (int ni = 0; ni < 4; ni++) {
                int r = wn + ni * 16 + fr;
                int cb = (ks * 64 + fq * 16) ^ ((r & 7) << 4);
                bfv[ni] = *reinterpret_cast<const bf16x8*>(reinterpret_cast<const char*>(Bs) + r * 128 + cb);
            }
            __builtin_amdgcn_s_setprio(1);
#pragma unroll
            for (int mi = 0; mi < 4; mi++)
#pragma unroll
                for (int ni = 0; ni < 4; ni++) acc[mi][ni] = mfma16(af[mi], bfv[ni], acc[mi][ni]);
            __builtin_amdgcn_s_setprio(0);
        }
        __syncthreads();  // reads done before next tile's gload_lds overwrites
    }

#pragma unroll
    for (int ni = 0; ni < 4; ni++) {
        const int col = n0 + wn + ni * 16 + fr;
        const float bb = bias[col];
#pragma unroll
        for (int mi = 0; mi < 4; mi++) {
            const int mrow = m0 + wm + mi * 16 + fq * 4;
            f32x4 v = acc[mi][ni];
            if (OUTBF16) {
                if (QKV && z == 2) {
                    const int b = mrow >> 11, s = mrow & (S_ - 1);
                    const int h = col >> 7, d = col & (DH - 1);
                    bf16x4 w = { (bf16_t)(v[0] + bb), (bf16_t)(v[1] + bb),
                                 (bf16_t)(v[2] + bb), (bf16_t)(v[3] + bb) };
                    *reinterpret_cast<bf16x4*>(Vt + ((size_t)((b * H_ + h) * DH + d)) * S_ + s) = w;
                } else {
                    bf16_t* Cz = Cqk + (size_t)z * M_ * N;
#pragma unroll
                    for (int j = 0; j < 4; j++)
                        Cz[(size_t)(mrow + j) * N + col] = (bf16_t)(v[j] + bb);
                }
            } else {
#pragma unroll
                for (int j = 0; j < 4; j++) Cf[(size_t)(mrow + j) * N + col] = v[j] + bb;
            }
        }
    }
}

// ---------------- causal flash attention, v5 ----------------
// v5: 8-wave (512-thread) blocks — 2 waves/SIMD guaranteed WITHIN one block, since
// R4/R5 showed the scheduler never co-schedules a 2nd block regardless of LDS.
// 256 blocks (1/CU): id -> bh = id&31, pr = id>>5; block processes q-tiles {pr, 15-pr}
// (128 rows each) sequentially -> exactly 34 kv-tiles of 64 per block, perfectly balanced.
// Each wave owns 16 q-rows. KVBLK=64, R4's verified swizzles: K rows 256B ^(r&7) on 16B
// chunks (low 3 bits), V rows 128B ^(rv&7), Pl rows 128B ^(fr&7). Blocks sharing (b,h)
// K/V have ids congruent mod 32 -> same XCD -> L2-local. Defer-max (T13), setprio (T5).
constexpr int KVBUF = 64 * 128 * (int)sizeof(bf16_t);  // 16384 B per buffer

__global__ __launch_bounds__(512, 2) void attn(
    const bf16_t* __restrict__ Q, const bf16_t* __restrict__ Kc,
    const bf16_t* __restrict__ Vt, bf16_t* __restrict__ Ctx) {
    const int id = blockIdx.x;
    const int bh = id & 31, b = bh >> 4, h = bh & 15;
    const int pr = id >> 5;
    const int lane = threadIdx.x & 63, wave = threadIdx.x >> 6;
    const int fr = lane & 15, fq = lane >> 4;

    __shared__ bf16_t Ks[2][64 * 128];   // 32 KB
    __shared__ bf16_t Vs[2][128 * 64];   // 32 KB
    __shared__ bf16_t Pl[8][16][64];     // 16 KB, XOR-swizzled rows of 128 B

    const bf16_t* Kbase = Kc + (size_t)b * S_ * AF + h * DH;
    const bf16_t* Vbase = Vt + (size_t)bh * DH * S_;
    const float scale = 0.022097086912079608f;  // 1/sqrt(2048)
    const f32x4 fz = {0.f, 0.f, 0.f, 0.f};

    // 512 threads stage K [64 kv][128 dh] (1024 chunks) + V [128 d][64 kv] (1024 chunks),
    // 2 chunks each; LDS dest linear (wave-uniform base + lane*16), source pre-swizzled.
    auto stage = [&](int buf, int kv0) {
#pragma unroll
        for (int i = 0; i < 2; ++i) {
            const int c = (int)threadIdx.x + 512 * i;   // 0..1023
            const int r = c >> 4, cc = c & 15;          // K row, 16B-chunk in 256B row
            gload16(Kbase + (size_t)(kv0 + r) * AF + ((cc ^ (r & 7)) << 3),
                    (char*)Ks + buf * KVBUF + c * 16);
            const int rv = c >> 3, cv = c & 7;          // V row, 16B-chunk in 128B row
            gload16(Vbase + (size_t)rv * S_ + kv0 + ((cv ^ (rv & 7)) << 3),
                    (char*)Vs + buf * KVBUF + c * 16);
        }
    };

    char* PlB = reinterpret_cast<char*>(Pl) + wave * 2048;

    for (int ph = 0; ph < 2; ++ph) {
        const int qt = ph ? (15 - pr) : pr;
        const int q0 = qt * 128;
        const int NT = 2 * qt + 2;

        // Q fragments: this wave's 16 q-rows are q0 + wave*16 + fr
        bf16x8 qf[4];
        {
            const bf16_t* qp = Q + (size_t)(b * S_ + q0 + wave * 16 + fr) * AF + h * DH + fq * 8;
#pragma unroll
            for (int ds = 0; ds < 4; ++ds) qf[ds] = *reinterpret_cast<const bf16x8*>(qp + ds * 32);
        }
        float m_ = -3.0e38f, l_ = 0.f;
        f32x4 o[8];
#pragma unroll
        for (int d = 0; d < 8; ++d) o[d] = fz;

        __syncthreads();           // buffers free from previous phase
        stage(0, 0);
        __syncthreads();           // tile 0 ready

        for (int t = 0; t < NT; ++t) {
            const int cur = t & 1;
            if (t + 1 < NT) stage(cur ^ 1, (t + 1) * 64);
            const int kv0 = t * 64;
            const char* kb = (const char*)Ks + cur * KVBUF;
            const char* vb = (const char*)Vs + cur * KVBUF;

            // ---- QK^T (swapped: A=K rows, B=Q rows) -> sv[kvf][r]: kv=kvf*16+fq*4+r, q=fr ----
            f32x4 sv[4];
            __builtin_amdgcn_s_setprio(1);
#pragma unroll
            for (int kvf = 0; kvf < 4; ++kvf) {
                bf16x8 kf[4];
#pragma unroll
                for (int ds = 0; ds < 4; ++ds) {
                    const int r = kvf * 16 + fr;
                    kf[ds] = *reinterpret_cast<const bf16x8*>(kb + r * 256 + ((ds * 64 + fq * 16) ^ ((r & 7) << 4)));
                }
                sv[kvf] = fz;
#pragma unroll
                for (int ds = 0; ds < 4; ++ds) sv[kvf] = mfma16(kf[ds], qf[ds], sv[kvf]);
            }
            __builtin_amdgcn_s_setprio(0);
            const bool diag = (t >= 2 * qt);

            // ---- softmax: lane owns 16 scores of q-row q0 + wave*16 + fr ----
            const int q_abs = q0 + wave * 16 + fr;
            float x[16], mx = -3.0e38f;
#pragma unroll
            for (int kvf = 0; kvf < 4; ++kvf)
#pragma unroll
                for (int r = 0; r < 4; ++r) {
                    float tv = sv[kvf][r] * scale;
                    if (diag && (kv0 + kvf * 16 + fq * 4 + r > q_abs)) tv = -3.0e38f;
                    x[kvf * 4 + r] = tv;
                    mx = fmaxf(mx, tv);
                }
            mx = fmaxf(mx, __shfl_xor(mx, 16, 64));
            mx = fmaxf(mx, __shfl_xor(mx, 32, 64));
            float mnew = m_;
            if (!__all(mx <= m_ + 8.f)) {   // defer-max (T13)
                mnew = fmaxf(m_, mx);
                const float corr = __expf(m_ - mnew);
                l_ *= corr;
                float cr[4];
#pragma unroll
                for (int r = 0; r < 4; ++r) cr[r] = __shfl(corr, fq * 4 + r, 64);
#pragma unroll
                for (int d = 0; d < 8; ++d)
#pragma unroll
                    for (int r = 0; r < 4; ++r) o[d][r] *= cr[r];
                m_ = mnew;
            }
            float rs = 0.f;
#pragma unroll
            for (int jj = 0; jj < 16; ++jj) { x[jj] = __expf(x[jj] - mnew); rs += x[jj]; }
            rs += __shfl_xor(rs, 16, 64);
            rs += __shfl_xor(rs, 32, 64);
            l_ += rs;
            // P -> LDS (row q=fr, 128-B rows, both-sides swizzle ^((fr&7)<<4) on 16B chunks)
#pragma unroll
            for (int kvf = 0; kvf < 4; ++kvf) {
                bf16x4 pw = { (bf16_t)x[kvf * 4 + 0], (bf16_t)x[kvf * 4 + 1],
                              (bf16_t)x[kvf * 4 + 2], (bf16_t)x[kvf * 4 + 3] };
                *reinterpret_cast<bf16x4*>(
                    PlB + fr * 128 + ((kvf * 32 + fq * 8) ^ ((fr & 7) << 4))) = pw;
            }

            // ---- PV: A = P (rows q), B = Vt (rows d) ----
#pragma unroll
            for (int ks = 0; ks < 2; ++ks) {
                const bf16x8 pa = *reinterpret_cast<const bf16x8*>(
                    PlB + fr * 128 + ((ks * 64 + fq * 16) ^ ((fr & 7) << 4)));
                __builtin_amdgcn_s_setprio(1);
#pragma unroll
                for (int d = 0; d < 8; ++d) {
                    const int rv = d * 16 + fr;
                    const bf16x8 vf = *reinterpret_cast<const bf16x8*>(
                        vb + rv * 128 + ((ks * 64 + fq * 16) ^ ((rv & 7) << 4)));
                    o[d] = mfma16(pa, vf, o[d]);
                }
                __builtin_amdgcn_s_setprio(0);
            }
            __syncthreads();  // next tile staged & current reads done
        }

        // ---- epilogue: o rows are q = q0 + wave*16 + fq*4 + r ----
        float li[4];
#pragma unroll
        for (int r = 0; r < 4; ++r) li[r] = 1.0f / __shfl(l_, fq * 4 + r, 64);
#pragma unroll
        for (int d = 0; d < 8; ++d)
#pragma unroll
            for (int r = 0; r < 4; ++r) {
                const size_t row = (size_t)(b * S_ + q0 + wave * 16 + fq * 4 + r);
                Ctx[row * AF + h * DH + d * 16 + fr] = (bf16_t)(o[d][r] * li[r]);
            }
    }
}

extern "C" void kernel_launch(void* const* d_in, const int* in_sizes, int n_in,
                              void* d_out, int out_size, void* d_ws, size_t ws_size,
                              hipStream_t stream) {
    const float* query = (const float*)d_in[0];
    const float* Wq = (const float*)d_in[1];
    const float* bq = (const float*)d_in[2];
    const float* Wk = (const float*)d_in[3];
    const float* bk = (const float*)d_in[4];
    const float* Wv = (const float*)d_in[5];
    const float* bv = (const float*)d_in[6];
    const float* Wo = (const float*)d_in[7];
    const float* bo = (const float*)d_in[8];
    float* out = (float*)d_out;
    char* ws = (char*)d_ws;

    bf16_t* xbf  = (bf16_t*)(ws + 0);
    bf16_t* wtq  = (bf16_t*)(ws + 8388608);
    bf16_t* wto  = (bf16_t*)(ws + 20971520);
    bf16_t* qws  = (bf16_t*)(ws + 25165824);
    bf16_t* vtws = (bf16_t*)(ws + 58720256);
    bf16_t* ctx  = (bf16_t*)(ws + 0);

    cvt_f32_to_bf16<<<4096, 256, 0, stream>>>(query, xbf);
    transpose_to_bf16<<<dim3(64, 32), 256, 0, stream>>>(Wq, wtq, 1024, 2048);
    transpose_to_bf16<<<dim3(64, 32), 256, 0, stream>>>(Wk, wtq + 2097152, 1024, 2048);
    transpose_to_bf16<<<dim3(64, 32), 256, 0, stream>>>(Wv, wtq + 2 * 2097152, 1024, 2048);
    transpose_to_bf16<<<dim3(32, 64), 256, 0, stream>>>(Wo, wto, 2048, 1024);

    gemm128<1024, 2048, true, true><<<dim3(16, 32, 3), 256, 0, stream>>>(
        xbf, wtq, bq, bk, bv, qws, vtws, nullptr);

    attn<<<256, 512, 0, stream>>>(qws, qws + (size_t)4096 * 2048, vtws, ctx);

    gemm128<2048, 1024, false, false><<<dim3(8, 32, 1), 256, 0, stream>>>(
        ctx, wto, bo, bo, bo, nullptr, nullptr, out);
}

// Round 7
// 181.531 us; speedup vs baseline: 1.2376x; 1.0396x over previous
//
#include <hip/hip_runtime.h>

typedef __bf16 bf16_t;
typedef __bf16 bf16x8 __attribute__((ext_vector_type(8)));
typedef __bf16 bf16x4 __attribute__((ext_vector_type(4)));
typedef float f32x4 __attribute__((ext_vector_type(4)));

static __device__ __forceinline__ f32x4 mfma16(bf16x8 a, bf16x8 b, f32x4 c) {
    return __builtin_amdgcn_mfma_f32_16x16x32_bf16(a, b, c, 0, 0, 0);
}

#define AS1 __attribute__((address_space(1)))
#define AS3 __attribute__((address_space(3)))
static __device__ __forceinline__ void gload16(const void* g, void* l) {
    __builtin_amdgcn_global_load_lds((AS1 const void*)g, (AS3 void*)l, 16, 0, 0);
}

constexpr int B_ = 2, S_ = 2048, H_ = 16, DH = 128, AF = 2048;
constexpr int M_ = B_ * S_;  // 4096

// ---------------- f32 -> bf16 convert (query) ----------------
__global__ void cvt_f32_to_bf16(const float* __restrict__ in, bf16_t* __restrict__ out) {
    int i = (blockIdx.x * 256 + threadIdx.x) * 4;
    const float4 v = *reinterpret_cast<const float4*>(in + i);
    bf16x4 o = { (bf16_t)v.x, (bf16_t)v.y, (bf16_t)v.z, (bf16_t)v.w };
    *reinterpret_cast<bf16x4*>(out + i) = o;
}

// ---------------- f32 [R][C] -> bf16 [C][R] transpose ----------------
__global__ void transpose_to_bf16(const float* __restrict__ in, bf16_t* __restrict__ out,
                                  int R, int C) {
    __shared__ float t[32][33];
    int c0 = blockIdx.x * 32, r0 = blockIdx.y * 32;
    int tx = threadIdx.x & 31, ty = threadIdx.x >> 5;  // 32 x 8
#pragma unroll
    for (int i = 0; i < 4; i++) t[ty + i * 8][tx] = in[(size_t)(r0 + ty + i * 8) * C + c0 + tx];
    __syncthreads();
#pragma unroll
    for (int i = 0; i < 4; i++)
        out[(size_t)(c0 + ty + i * 8) * R + r0 + tx] = (bf16_t)t[tx][ty + i * 8];
}

// ---------------- 128x128-tile bf16 GEMM: C = A[M][K] * Bt[N][K]^T + bias ----------------
// staging via global_load_lds width=16 (linear LDS dest, pre-swizzled source col).
template <int K, int N, bool OUTBF16, bool QKV>
__global__ __launch_bounds__(256) void gemm128(
    const bf16_t* __restrict__ A, const bf16_t* __restrict__ Bt,
    const float* __restrict__ b0, const float* __restrict__ b1, const float* __restrict__ b2,
    bf16_t* __restrict__ Cqk, bf16_t* __restrict__ Vt, float* __restrict__ Cf) {
    __shared__ bf16_t As[128 * 64];
    __shared__ bf16_t Bs[128 * 64];
    const int z = blockIdx.z;
    const bf16_t* Bz = Bt + (size_t)z * N * K;
    const float* bias = (z == 0) ? b0 : (z == 1 ? b1 : b2);
    const int m0 = blockIdx.y * 128, n0 = blockIdx.x * 128;
    const int tid = threadIdx.x, lane = tid & 63, wave = tid >> 6;
    const int wm = (wave >> 1) * 64, wn = (wave & 1) * 64;
    const int fr = lane & 15, fq = lane >> 4;

    f32x4 acc[4][4];
    const f32x4 fz = {0.f, 0.f, 0.f, 0.f};
#pragma unroll
    for (int i = 0; i < 4; i++)
#pragma unroll
        for (int j = 0; j < 4; j++) acc[i][j] = fz;

    for (int kt = 0; kt < K / 64; ++kt) {
        const int k0 = kt * 64;
#pragma unroll
        for (int j = 0; j < 4; j++) {
            int cid = tid + 256 * j;
            int r = cid >> 3;
            int sc = ((cid & 7) ^ (r & 7)) << 3;
            gload16(A + (size_t)(m0 + r) * K + k0 + sc, (char*)As + cid * 16);
            gload16(Bz + (size_t)(n0 + r) * K + k0 + sc, (char*)Bs + cid * 16);
        }
        __syncthreads();
#pragma unroll
        for (int ks = 0; ks < 2; ++ks) {
            bf16x8 af[4], bfv[4];
#pragma unroll
            for (int mi = 0; mi < 4; mi++) {
                int r = wm + mi * 16 + fr;
                int cb = (ks * 64 + fq * 16) ^ ((r & 7) << 4);
                af[mi] = *reinterpret_cast<const bf16x8*>(reinterpret_cast<const char*>(As) + r * 128 + cb);
            }
#pragma unroll
            for (int ni = 0; ni < 4; ni++) {
                int r = wn + ni * 16 + fr;
                int cb = (ks * 64 + fq * 16) ^ ((r & 7) << 4);
                bfv[ni] = *reinterpret_cast<const bf16x8*>(reinterpret_cast<const char*>(Bs) + r * 128 + cb);
            }
            __builtin_amdgcn_s_setprio(1);
#pragma unroll
            for (int mi = 0; mi < 4; mi++)
#pragma unroll
                for (int ni = 0; ni < 4; ni++) acc[mi][ni] = mfma16(af[mi], bfv[ni], acc[mi][ni]);
            __builtin_amdgcn_s_setprio(0);
        }
        __syncthreads();
    }

#pragma unroll
    for (int ni = 0; ni < 4; ni++) {
        const int col = n0 + wn + ni * 16 + fr;
        const float bb = bias[col];
#pragma unroll
        for (int mi = 0; mi < 4; mi++) {
            const int mrow = m0 + wm + mi * 16 + fq * 4;
            f32x4 v = acc[mi][ni];
            if (OUTBF16) {
                if (QKV && z == 2) {
                    const int b = mrow >> 11, s = mrow & (S_ - 1);
                    const int h = col >> 7, d = col & (DH - 1);
                    bf16x4 w = { (bf16_t)(v[0] + bb), (bf16_t)(v[1] + bb),
                                 (bf16_t)(v[2] + bb), (bf16_t)(v[3] + bb) };
                    *reinterpret_cast<bf16x4*>(Vt + ((size_t)((b * H_ + h) * DH + d)) * S_ + s) = w;
                } else {
                    bf16_t* Cz = Cqk + (size_t)z * M_ * N;
#pragma unroll
                    for (int j = 0; j < 4; j++)
                        Cz[(size_t)(mrow + j) * N + col] = (bf16_t)(v[j] + bb);
                }
            } else {
#pragma unroll
                for (int j = 0; j < 4; j++) Cf[(size_t)(mrow + j) * N + col] = v[j] + bb;
            }
        }
    }
}

// ---------------- causal flash attention, v6 ----------------
// v6: FLOP-per-LDS-byte fix. 8 waves = 4 q-waves x 2 kv-streams; each wave owns 32 q-rows
// (2 qg of 16) so each K/V fragment read feeds 2x the MFMAs (R6 floor was per-wave K/V
// re-reads). Stream s handles tiles 2k+s; NT=2qt+2 splits evenly; 17 steps vs R6's 34.
// P stays in REGISTERS: cvt_pk to bf16 pairs + 8 shfl + 4 selects per (qg,ks) rearrange
// P into the PV A-fragment layout (no Pl LDS). LDS = 128KB: K[2 strm][2 dbuf] + V same.
// Streams merge (m,l,O) once per phase via LDS (aliases K/V region, barrier-protected).
// m init = -88 (not -3e38): cold fully-masked tiles give exp->0, not exp(0)=1.
constexpr int TS_ = 16384;  // one 64x128 bf16 tile in LDS

__global__ __launch_bounds__(512, 2) void attn(
    const bf16_t* __restrict__ Q, const bf16_t* __restrict__ Kc,
    const bf16_t* __restrict__ Vt, bf16_t* __restrict__ Ctx) {
    const int id = blockIdx.x;
    const int bh = id & 31, b = bh >> 4, h = bh & 15;
    const int pr = id >> 5;
    const int lane = threadIdx.x & 63, wave = threadIdx.x >> 6;
    const int fr = lane & 15, fq = lane >> 4;
    const int qw = wave & 3, strm = wave >> 2;

    __shared__ __align__(16) char L[131072];  // K bufs [s][p] @ (s*2+p)*TS_, V @ 65536+...

    const bf16_t* Kbase = Kc + (size_t)b * S_ * AF + h * DH;
    const bf16_t* Vbase = Vt + (size_t)bh * DH * S_;
    const float scale = 0.022097086912079608f;  // 1/sqrt(2048)
    const f32x4 fz = {0.f, 0.f, 0.f, 0.f};

    // stage K/V tiles t0 (stream0) and t0+1 (stream1) into buffer parity p
    auto stage = [&](int p, int t0) {
#pragma unroll
        for (int i = 0; i < 2; ++i) {
            const int c = (int)threadIdx.x + 512 * i;   // 0..1023
            const int r = c >> 4, cc = c & 15;          // K row, 16B chunk in 256B row
            gload16(Kbase + (size_t)(t0 * 64 + r) * AF + ((cc ^ (r & 7)) << 3),
                    L + (0 * 2 + p) * TS_ + c * 16);
            gload16(Kbase + (size_t)((t0 + 1) * 64 + r) * AF + ((cc ^ (r & 7)) << 3),
                    L + (1 * 2 + p) * TS_ + c * 16);
            const int rv = c >> 3, cv = c & 7;          // V row, 16B chunk in 128B row
            gload16(Vbase + (size_t)rv * S_ + t0 * 64 + ((cv ^ (rv & 7)) << 3),
                    L + 65536 + (0 * 2 + p) * TS_ + c * 16);
            gload16(Vbase + (size_t)rv * S_ + (t0 + 1) * 64 + ((cv ^ (rv & 7)) << 3),
                    L + 65536 + (1 * 2 + p) * TS_ + c * 16);
        }
    };

    for (int ph = 0; ph < 2; ++ph) {
        const int qt = ph ? (15 - pr) : pr;
        const int q0 = qt * 128;
        const int nst = qt + 1;   // steps; each step = 2 tiles (one per stream)

        // Q fragments: wave rows q0 + qw*32 + qg*16 + fr
        bf16x8 qf[2][4];
#pragma unroll
        for (int qg = 0; qg < 2; ++qg) {
            const bf16_t* qp = Q + (size_t)(b * S_ + q0 + qw * 32 + qg * 16 + fr) * AF + h * DH + fq * 8;
#pragma unroll
            for (int ds = 0; ds < 4; ++ds) qf[qg][ds] = *reinterpret_cast<const bf16x8*>(qp + ds * 32);
        }
        float m_[2] = {-88.f, -88.f}, l_[2] = {0.f, 0.f};
        f32x4 o[2][8];
#pragma unroll
        for (int qg = 0; qg < 2; ++qg)
#pragma unroll
            for (int d = 0; d < 8; ++d) o[qg][d] = fz;

        __syncthreads();           // L free (prev phase merge done)
        stage(0, 0);
        __syncthreads();           // step-0 tiles ready

        for (int k = 0; k < nst; ++k) {
            if (k + 1 < nst) stage((k + 1) & 1, 2 * k + 2);
            const int ts = 2 * k + strm;
            const int kv0 = ts * 64;
            const char* kb = L + (strm * 2 + (k & 1)) * TS_;
            const char* vb = L + 65536 + (strm * 2 + (k & 1)) * TS_;

            // ---- QK^T (swapped): sv[qg][kvf][r] = S[kv=kvf*16+fq*4+r][q=fr] ----
            f32x4 sv[2][4];
            __builtin_amdgcn_s_setprio(1);
#pragma unroll
            for (int kvf = 0; kvf < 4; ++kvf) {
                bf16x8 kf[4];
#pragma unroll
                for (int ds = 0; ds < 4; ++ds) {
                    const int r = kvf * 16 + fr;
                    kf[ds] = *reinterpret_cast<const bf16x8*>(kb + r * 256 + ((ds * 64 + fq * 16) ^ ((r & 7) << 4)));
                }
                sv[0][kvf] = fz; sv[1][kvf] = fz;
#pragma unroll
                for (int ds = 0; ds < 4; ++ds) {
                    sv[0][kvf] = mfma16(kf[ds], qf[0][ds], sv[0][kvf]);
                    sv[1][kvf] = mfma16(kf[ds], qf[1][ds], sv[1][kvf]);
                }
            }
            __builtin_amdgcn_s_setprio(0);
            const bool diag = (ts >= 2 * qt);

            // ---- softmax per qg; pack P to bf16-pair words (stays in registers) ----
            uint32_t pk[2][8];
#pragma unroll
            for (int qg = 0; qg < 2; ++qg) {
                const int q_abs = q0 + qw * 32 + qg * 16 + fr;
                float x[16], mx = -3.0e38f;
#pragma unroll
                for (int kvf = 0; kvf < 4; ++kvf)
#pragma unroll
                    for (int r = 0; r < 4; ++r) {
                        float tv = sv[qg][kvf][r] * scale;
                        if (diag && (kv0 + kvf * 16 + fq * 4 + r > q_abs)) tv = -3.0e38f;
                        x[kvf * 4 + r] = tv;
                        mx = fmaxf(mx, tv);
                    }
                mx = fmaxf(mx, __shfl_xor(mx, 16, 64));
                mx = fmaxf(mx, __shfl_xor(mx, 32, 64));
                float mnew = m_[qg];
                if (!__all(mx <= m_[qg] + 8.f)) {   // defer-max (T13)
                    mnew = fmaxf(m_[qg], mx);
                    const float corr = __expf(m_[qg] - mnew);
                    l_[qg] *= corr;
                    float cr[4];
#pragma unroll
                    for (int r = 0; r < 4; ++r) cr[r] = __shfl(corr, fq * 4 + r, 64);
#pragma unroll
                    for (int d = 0; d < 8; ++d)
#pragma unroll
                        for (int r = 0; r < 4; ++r) o[qg][d][r] *= cr[r];
                    m_[qg] = mnew;
                }
                float rs = 0.f;
#pragma unroll
                for (int jj = 0; jj < 16; ++jj) { x[jj] = __expf(x[jj] - mnew); rs += x[jj]; }
                rs += __shfl_xor(rs, 16, 64);
                rs += __shfl_xor(rs, 32, 64);
                l_[qg] += rs;
#pragma unroll
                for (int j = 0; j < 8; ++j)
                    asm("v_cvt_pk_bf16_f32 %0, %1, %2" : "=v"(pk[qg][j]) : "v"(x[2 * j]), "v"(x[2 * j + 1]));
            }

            // ---- PV: P moved to A-frag layout via shfl (lane(fr,fq) word w needs
            //      pk[ks*4+(fqT>>1)*2+(w&1)] from lane (fq&1)*32+(w>>1)*16+fr) ----
#pragma unroll
            for (int ks = 0; ks < 2; ++ks) {
                bf16x8 pa[2];
#pragma unroll
                for (int qg = 0; qg < 2; ++qg) {
                    union { uint32_t w[4]; bf16x8 v; } u;
#pragma unroll
                    for (int w = 0; w < 4; ++w) {
                        const int sl = (fq & 1) * 32 + (w >> 1) * 16 + fr;
                        const int a0 = __shfl((int)pk[qg][ks * 4 + (w & 1)], sl, 64);
                        const int a1 = __shfl((int)pk[qg][ks * 4 + 2 + (w & 1)], sl, 64);
                        u.w[w] = (uint32_t)((fq >> 1) ? a1 : a0);
                    }
                    pa[qg] = u.v;
                }
                __builtin_amdgcn_s_setprio(1);
#pragma unroll
                for (int d = 0; d < 8; ++d) {
                    const int rv = d * 16 + fr;
                    const bf16x8 vf = *reinterpret_cast<const bf16x8*>(
                        vb + rv * 128 + ((ks * 64 + fq * 16) ^ ((rv & 7) << 4)));
                    o[0][d] = mfma16(pa[0], vf, o[0][d]);
                    o[1][d] = mfma16(pa[1], vf, o[1][d]);
                }
                __builtin_amdgcn_s_setprio(0);
            }
            __syncthreads();  // next step staged & current reads done
        }

        // ---- stream merge + epilogue (LDS aliases K/V region) ----
        if (strm == 1) {
#pragma unroll
            for (int qg = 0; qg < 2; ++qg) {
#pragma unroll
                for (int d = 0; d < 8; ++d)
                    *reinterpret_cast<f32x4*>(L + qw * 16384 + (qg * 8 + d) * 1024 + lane * 16) = o[qg][d];
                float2 ml = { m_[qg], l_[qg] };
                *reinterpret_cast<float2*>(L + 65536 + ((qw * 2 + qg) * 64 + lane) * 8) = ml;
            }
        }
        __syncthreads();
        if (strm == 0) {
#pragma unroll
            for (int qg = 0; qg < 2; ++qg) {
                float c0[4], c1[4], li[4];
#pragma unroll
                for (int r = 0; r < 4; ++r) {
                    const float2 ml1 = *reinterpret_cast<const float2*>(
                        L + 65536 + ((qw * 2 + qg) * 64 + (fq * 4 + r)) * 8);
                    const float m0r = __shfl(m_[qg], fq * 4 + r, 64);
                    const float l0r = __shfl(l_[qg], fq * 4 + r, 64);
                    const float mm = fmaxf(m0r, ml1.x);
                    c0[r] = __expf(m0r - mm);
                    c1[r] = __expf(ml1.x - mm);
                    li[r] = 1.0f / (l0r * c0[r] + ml1.y * c1[r]);
                }
#pragma unroll
                for (int d = 0; d < 8; ++d) {
                    const f32x4 o1 = *reinterpret_cast<const f32x4*>(
                        L + qw * 16384 + (qg * 8 + d) * 1024 + lane * 16);
#pragma unroll
                    for (int r = 0; r < 4; ++r) {
                        const size_t row = (size_t)(b * S_ + q0 + qw * 32 + qg * 16 + fq * 4 + r);
                        Ctx[row * AF + h * DH + d * 16 + fr] =
                            (bf16_t)((o[qg][d][r] * c0[r] + o1[r] * c1[r]) * li[r]);
                    }
                }
            }
        }
        __syncthreads();  // L reused by next phase staging
    }
}

extern "C" void kernel_launch(void* const* d_in, const int* in_sizes, int n_in,
                              void* d_out, int out_size, void* d_ws, size_t ws_size,
                              hipStream_t stream) {
    const float* query = (const float*)d_in[0];
    const float* Wq = (const float*)d_in[1];
    const float* bq = (const float*)d_in[2];
    const float* Wk = (const float*)d_in[3];
    const float* bk = (const float*)d_in[4];
    const float* Wv = (const float*)d_in[5];
    const float* bv = (const float*)d_in[6];
    const float* Wo = (const float*)d_in[7];
    const float* bo = (const float*)d_in[8];
    float* out = (float*)d_out;
    char* ws = (char*)d_ws;

    bf16_t* xbf  = (bf16_t*)(ws + 0);
    bf16_t* wtq  = (bf16_t*)(ws + 8388608);
    bf16_t* wto  = (bf16_t*)(ws + 20971520);
    bf16_t* qws  = (bf16_t*)(ws + 25165824);
    bf16_t* vtws = (bf16_t*)(ws + 58720256);
    bf16_t* ctx  = (bf16_t*)(ws + 0);

    cvt_f32_to_bf16<<<4096, 256, 0, stream>>>(query, xbf);
    transpose_to_bf16<<<dim3(64, 32), 256, 0, stream>>>(Wq, wtq, 1024, 2048);
    transpose_to_bf16<<<dim3(64, 32), 256, 0, stream>>>(Wk, wtq + 2097152, 1024, 2048);
    transpose_to_bf16<<<dim3(64, 32), 256, 0, stream>>>(Wv, wtq + 2 * 2097152, 1024, 2048);
    transpose_to_bf16<<<dim3(32, 64), 256, 0, stream>>>(Wo, wto, 2048, 1024);

    gemm128<1024, 2048, true, true><<<dim3(16, 32, 3), 256, 0, stream>>>(
        xbf, wtq, bq, bk, bv, qws, vtws, nullptr);

    attn<<<256, 512, 0, stream>>>(qws, qws + (size_t)4096 * 2048, vtws, ctx);

    gemm128<2048, 1024, false, false><<<dim3(8, 32, 1), 256, 0, stream>>>(
        ctx, wto, bo, bo, bo, nullptr, nullptr, out);
}